// Round 1
// baseline (90.924 us; speedup 1.0000x reference)
//
#include <hip/hip_runtime.h>
#include <math.h>

#define HDIM 1024
#define EDIM 1024
#define TDIM 4096
#define VDIM 50257
#define INPDIM 2049
#define STRIPES 64
#define ROWS_PER_STRIPE (TDIM / STRIPES)   // 64
#define NBLK_V ((VDIM + 255) / 256)        // 197

// K1: striped column-sum of hiddens [T,E] -> partial[STRIPES][E]
__global__ __launch_bounds__(256) void k1_colsum(const float* __restrict__ hiddens,
                                                 float* __restrict__ partial) {
    int st = blockIdx.x;      // stripe
    int t  = threadIdx.x;     // 0..255, each handles 4 cols via float4
    const float4* hp = reinterpret_cast<const float4*>(hiddens + (size_t)st * ROWS_PER_STRIPE * EDIM);
    float4 acc = {0.f, 0.f, 0.f, 0.f};
    for (int r = 0; r < ROWS_PER_STRIPE; ++r) {
        float4 v = hp[r * (EDIM / 4) + t];
        acc.x += v.x; acc.y += v.y; acc.z += v.z; acc.w += v.w;
    }
    reinterpret_cast<float4*>(partial + st * EDIM)[t] = acc;
}

// K2: reduce partials over stripes, build x = [sen_emb, colsum, pos_index]
__global__ __launch_bounds__(256) void k2_buildx(const float* __restrict__ partial,
                                                 const float* __restrict__ sen_emb,
                                                 const int* __restrict__ pos_index,
                                                 float* __restrict__ x) {
    int col = blockIdx.x * 256 + threadIdx.x;  // 0..1023
    float s = 0.f;
    for (int st = 0; st < STRIPES; ++st) s += partial[st * EDIM + col];
    x[col] = sen_emb[col];
    x[EDIM + col] = s;
    if (col == 0) x[2048] = (float)(*pos_index);
}

// K3: LSTM gates. One block per output row j; wave w computes gate w.
__global__ __launch_bounds__(256) void k3_gates(
    const float* __restrict__ x, const float* __restrict__ cur_h,
    const float* __restrict__ cur_cell,
    const float* __restrict__ Wi0, const float* __restrict__ Wh0,
    const float* __restrict__ bi0, const float* __restrict__ bh0,
    const float* __restrict__ Wi1, const float* __restrict__ Wh1,
    const float* __restrict__ bi1, const float* __restrict__ bh1,
    const float* __restrict__ Wi2, const float* __restrict__ Wh2,
    const float* __restrict__ bi2, const float* __restrict__ bh2,
    const float* __restrict__ Wi3, const float* __restrict__ Wh3,
    const float* __restrict__ bi3, const float* __restrict__ bh3,
    float* __restrict__ hout) {
    int j = blockIdx.x;
    int wave = threadIdx.x >> 6;
    int lane = threadIdx.x & 63;

    const float* Wi = (wave == 0 ? Wi0 : wave == 1 ? Wi1 : wave == 2 ? Wi2 : Wi3);
    const float* Wh = (wave == 0 ? Wh0 : wave == 1 ? Wh1 : wave == 2 ? Wh2 : Wh3);
    const float* bi = (wave == 0 ? bi0 : wave == 1 ? bi1 : wave == 2 ? bi2 : bi3);
    const float* bh = (wave == 0 ? bh0 : wave == 1 ? bh1 : wave == 2 ? bh2 : bh3);

    const float* wi_row = Wi + (size_t)j * INPDIM;
    const float* wh_row = Wh + (size_t)j * HDIM;

    float acc = 0.f;
    for (int k = lane; k < INPDIM; k += 64) acc = fmaf(wi_row[k], x[k], acc);
    for (int k = lane; k < HDIM; k += 64)  acc = fmaf(wh_row[k], cur_h[k], acc);
    #pragma unroll
    for (int o = 32; o; o >>= 1) acc += __shfl_xor(acc, o, 64);

    __shared__ float g[4];
    if (lane == 0) g[wave] = acc + bi[j] + bh[j];
    __syncthreads();
    if (threadIdx.x == 0) {
        float iv = 1.f / (1.f + expf(-g[0]));
        float fv = 1.f / (1.f + expf(-g[1]));
        float gv = tanhf(g[2]);
        float ov = 1.f / (1.f + expf(-g[3]));
        float c  = fv * cur_cell[j] + iv * gv;
        hout[j]  = ov * tanhf(c);
    }
}

// K4: logits[v] = dot(h, dim_out[:,v]) -> d_out; per-block max + sum(exp) partials
__global__ __launch_bounds__(256) void k4_logits(const float* __restrict__ hvec,
                                                 const float* __restrict__ dim_out,
                                                 float* __restrict__ logits,
                                                 float* __restrict__ pmax,
                                                 float* __restrict__ psum) {
    __shared__ float sh[HDIM];
    __shared__ float red[4];
    int t = threadIdx.x;
    for (int k = t; k < HDIM; k += 256) sh[k] = hvec[k];
    __syncthreads();

    int v = blockIdx.x * 256 + t;
    float acc = -INFINITY;
    if (v < VDIM) {
        const float* p = dim_out + v;
        float a = 0.f;
        #pragma unroll 16
        for (int k = 0; k < HDIM; ++k) a = fmaf(sh[k], p[(size_t)k * VDIM], a);
        logits[v] = a;
        acc = a;
    }
    int wave = t >> 6, lane = t & 63;
    // block max
    float m = acc;
    #pragma unroll
    for (int o = 32; o; o >>= 1) m = fmaxf(m, __shfl_xor(m, o, 64));
    if (lane == 0) red[wave] = m;
    __syncthreads();
    float bm = fmaxf(fmaxf(red[0], red[1]), fmaxf(red[2], red[3]));
    __syncthreads();
    // block sum of exp(l - bm)
    float s = (v < VDIM) ? expf(acc - bm) : 0.f;
    #pragma unroll
    for (int o = 32; o; o >>= 1) s += __shfl_xor(s, o, 64);
    if (lane == 0) red[wave] = s;
    __syncthreads();
    if (t == 0) {
        pmax[blockIdx.x] = bm;
        psum[blockIdx.x] = red[0] + red[1] + red[2] + red[3];
    }
}

// K5: every block re-reduces the 197 partials, then normalizes its slice in place
__global__ __launch_bounds__(256) void k5_softmax(const float* __restrict__ pmax,
                                                  const float* __restrict__ psum,
                                                  float* __restrict__ out) {
    __shared__ float lm[4], ls[4];
    int t = threadIdx.x;
    int wave = t >> 6, lane = t & 63;

    float m = (t < NBLK_V) ? pmax[t] : -INFINITY;
    float wm = m;
    #pragma unroll
    for (int o = 32; o; o >>= 1) wm = fmaxf(wm, __shfl_xor(wm, o, 64));
    if (lane == 0) lm[wave] = wm;
    __syncthreads();
    float M = fmaxf(fmaxf(lm[0], lm[1]), fmaxf(lm[2], lm[3]));

    float s = (t < NBLK_V) ? psum[t] * expf(m - M) : 0.f;
    #pragma unroll
    for (int o = 32; o; o >>= 1) s += __shfl_xor(s, o, 64);
    if (lane == 0) ls[wave] = s;
    __syncthreads();
    float S = ls[0] + ls[1] + ls[2] + ls[3];

    int v = blockIdx.x * 256 + t;
    if (v < VDIM) out[v] = expf(out[v] - M) / S;
}

extern "C" void kernel_launch(void* const* d_in, const int* in_sizes, int n_in,
                              void* d_out, int out_size, void* d_ws, size_t ws_size,
                              hipStream_t stream) {
    const float* sen_emb  = (const float*)d_in[0];
    const float* hiddens  = (const float*)d_in[1];
    const float* dim_out  = (const float*)d_in[2];
    const float* Wi[4]; const float* Wh[4]; const float* bi[4]; const float* bh[4];
    for (int g = 0; g < 4; ++g) {
        Wi[g] = (const float*)d_in[3 + 4 * g];
        Wh[g] = (const float*)d_in[4 + 4 * g];
        bi[g] = (const float*)d_in[5 + 4 * g];
        bh[g] = (const float*)d_in[6 + 4 * g];
    }
    const float* cur_h    = (const float*)d_in[19];
    const float* cur_cell = (const float*)d_in[20];
    const int*   pos_idx  = (const int*)d_in[21];
    float* out = (float*)d_out;
    float* ws  = (float*)d_ws;

    float* partial = ws;                           // 64*1024 = 65536 floats
    float* x       = ws + 65536;                   // 2049
    float* hv      = ws + 65536 + 2056;            // 1024
    float* pmax    = ws + 65536 + 2056 + 1024;     // 197 (padded to 256)
    float* psum    = pmax + 256;                   // 197

    k1_colsum<<<STRIPES, 256, 0, stream>>>(hiddens, partial);
    k2_buildx<<<4, 256, 0, stream>>>(partial, sen_emb, pos_idx, x);
    k3_gates<<<HDIM, 256, 0, stream>>>(x, cur_h, cur_cell,
        Wi[0], Wh[0], bi[0], bh[0],
        Wi[1], Wh[1], bi[1], bh[1],
        Wi[2], Wh[2], bi[2], bh[2],
        Wi[3], Wh[3], bi[3], bh[3], hv);
    k4_logits<<<NBLK_V, 256, 0, stream>>>(hv, dim_out, out, pmax, psum);
    k5_softmax<<<NBLK_V, 256, 0, stream>>>(pmax, psum, out);
}

// Round 2
// 69.211 us; speedup vs baseline: 1.3137x; 1.3137x over previous
//
#include <hip/hip_runtime.h>
#include <math.h>

#define HDIM 1024
#define EDIM 1024
#define TDIM 4096
#define VDIM 50257
#define INPDIM 2049
#define STRIPES 128
#define ROWS_PER_STRIPE (TDIM / STRIPES)   // 32
#define NBLK_V ((VDIM + 255) / 256)        // 197
#define KS 8                               // k-splits for logits
#define KCHUNK (HDIM / KS)                 // 128
#define PSTR (NBLK_V * 256)                // 50432, padded partial stride

// K1: striped column-sum of hiddens [T,E] -> partial[STRIPES][E]
__global__ __launch_bounds__(256) void k1_colsum(const float* __restrict__ hiddens,
                                                 float* __restrict__ partial) {
    int st = blockIdx.x;
    int t  = threadIdx.x;
    const float4* hp = reinterpret_cast<const float4*>(hiddens + (size_t)st * ROWS_PER_STRIPE * EDIM);
    float4 acc = {0.f, 0.f, 0.f, 0.f};
    #pragma unroll 8
    for (int r = 0; r < ROWS_PER_STRIPE; ++r) {
        float4 v = hp[r * (EDIM / 4) + t];
        acc.x += v.x; acc.y += v.y; acc.z += v.z; acc.w += v.w;
    }
    reinterpret_cast<float4*>(partial + st * EDIM)[t] = acc;
}

// K2: reduce partials over stripes, build x = [sen_emb, colsum, pos_index]
__global__ __launch_bounds__(256) void k2_buildx(const float* __restrict__ partial,
                                                 const float* __restrict__ sen_emb,
                                                 const int* __restrict__ pos_index,
                                                 float* __restrict__ x) {
    int col = blockIdx.x * 256 + threadIdx.x;  // 0..1023
    float s = 0.f;
    #pragma unroll 8
    for (int st = 0; st < STRIPES; ++st) s += partial[st * EDIM + col];
    x[col] = sen_emb[col];
    x[EDIM + col] = s;
    if (col == 0) x[2048] = (float)(*pos_index);
}

// K3: LSTM gates. One block per output row j; wave w computes gate w.
__global__ __launch_bounds__(256) void k3_gates(
    const float* __restrict__ x, const float* __restrict__ cur_h,
    const float* __restrict__ cur_cell,
    const float* __restrict__ Wi0, const float* __restrict__ Wh0,
    const float* __restrict__ bi0, const float* __restrict__ bh0,
    const float* __restrict__ Wi1, const float* __restrict__ Wh1,
    const float* __restrict__ bi1, const float* __restrict__ bh1,
    const float* __restrict__ Wi2, const float* __restrict__ Wh2,
    const float* __restrict__ bi2, const float* __restrict__ bh2,
    const float* __restrict__ Wi3, const float* __restrict__ Wh3,
    const float* __restrict__ bi3, const float* __restrict__ bh3,
    float* __restrict__ hout) {
    int j = blockIdx.x;
    int wave = threadIdx.x >> 6;
    int lane = threadIdx.x & 63;

    const float* Wi = (wave == 0 ? Wi0 : wave == 1 ? Wi1 : wave == 2 ? Wi2 : Wi3);
    const float* Wh = (wave == 0 ? Wh0 : wave == 1 ? Wh1 : wave == 2 ? Wh2 : Wh3);
    const float* bi = (wave == 0 ? bi0 : wave == 1 ? bi1 : wave == 2 ? bi2 : bi3);
    const float* bh = (wave == 0 ? bh0 : wave == 1 ? bh1 : wave == 2 ? bh2 : bh3);

    const float* wi_row = Wi + (size_t)j * INPDIM;
    const float* wh_row = Wh + (size_t)j * HDIM;

    float acc = 0.f;
    #pragma unroll 8
    for (int k = lane; k < 2048; k += 64) acc = fmaf(wi_row[k], x[k], acc);
    if (lane == 0) acc = fmaf(wi_row[2048], x[2048], acc);
    #pragma unroll 8
    for (int k = lane; k < HDIM; k += 64)  acc = fmaf(wh_row[k], cur_h[k], acc);
    #pragma unroll
    for (int o = 32; o; o >>= 1) acc += __shfl_xor(acc, o, 64);

    __shared__ float g[4];
    if (lane == 0) g[wave] = acc + bi[j] + bh[j];
    __syncthreads();
    if (threadIdx.x == 0) {
        float iv = 1.f / (1.f + expf(-g[0]));
        float fv = 1.f / (1.f + expf(-g[1]));
        float gv = tanhf(g[2]);
        float ov = 1.f / (1.f + expf(-g[3]));
        float c  = fv * cur_cell[j] + iv * gv;
        hout[j]  = ov * tanhf(c);
    }
}

// K4a: k-split partial logits. grid (NBLK_V, KS). part[ks][v] = dot over k-chunk.
__global__ __launch_bounds__(256) void k4a_partial(const float* __restrict__ hvec,
                                                   const float* __restrict__ dim_out,
                                                   float* __restrict__ part) {
    __shared__ float hs[KCHUNK];
    int t  = threadIdx.x;
    int ks = blockIdx.y;
    if (t < KCHUNK) hs[t] = hvec[ks * KCHUNK + t];
    __syncthreads();
    int v = blockIdx.x * 256 + t;
    if (v < VDIM) {
        const float* p = dim_out + (size_t)ks * KCHUNK * VDIM + v;
        float a = 0.f;
        #pragma unroll 16
        for (int k = 0; k < KCHUNK; ++k) { a = fmaf(hs[k], *p, a); p += VDIM; }
        part[ks * PSTR + v] = a;
    }
}

// K4b: combine k-splits -> logits in d_out; per-block max + sum(exp) partials
__global__ __launch_bounds__(256) void k4b_combine(const float* __restrict__ part,
                                                   float* __restrict__ logits,
                                                   float* __restrict__ pmax,
                                                   float* __restrict__ psum) {
    __shared__ float red[4];
    int t = threadIdx.x;
    int v = blockIdx.x * 256 + t;
    float acc = -INFINITY;
    if (v < VDIM) {
        float a = 0.f;
        #pragma unroll
        for (int ks = 0; ks < KS; ++ks) a += part[ks * PSTR + v];
        logits[v] = a;
        acc = a;
    }
    int wave = t >> 6, lane = t & 63;
    float m = acc;
    #pragma unroll
    for (int o = 32; o; o >>= 1) m = fmaxf(m, __shfl_xor(m, o, 64));
    if (lane == 0) red[wave] = m;
    __syncthreads();
    float bm = fmaxf(fmaxf(red[0], red[1]), fmaxf(red[2], red[3]));
    __syncthreads();
    float s = (v < VDIM) ? expf(acc - bm) : 0.f;
    #pragma unroll
    for (int o = 32; o; o >>= 1) s += __shfl_xor(s, o, 64);
    if (lane == 0) red[wave] = s;
    __syncthreads();
    if (t == 0) {
        pmax[blockIdx.x] = bm;
        psum[blockIdx.x] = red[0] + red[1] + red[2] + red[3];
    }
}

// K5: every block re-reduces the 197 partials, then normalizes its slice in place
__global__ __launch_bounds__(256) void k5_softmax(const float* __restrict__ pmax,
                                                  const float* __restrict__ psum,
                                                  float* __restrict__ out) {
    __shared__ float lm[4], ls[4];
    int t = threadIdx.x;
    int wave = t >> 6, lane = t & 63;

    float m = (t < NBLK_V) ? pmax[t] : -INFINITY;
    float wm = m;
    #pragma unroll
    for (int o = 32; o; o >>= 1) wm = fmaxf(wm, __shfl_xor(wm, o, 64));
    if (lane == 0) lm[wave] = wm;
    __syncthreads();
    float M = fmaxf(fmaxf(lm[0], lm[1]), fmaxf(lm[2], lm[3]));

    float s = (t < NBLK_V) ? psum[t] * expf(m - M) : 0.f;
    #pragma unroll
    for (int o = 32; o; o >>= 1) s += __shfl_xor(s, o, 64);
    if (lane == 0) ls[wave] = s;
    __syncthreads();
    float S = ls[0] + ls[1] + ls[2] + ls[3];

    int v = blockIdx.x * 256 + t;
    if (v < VDIM) out[v] = expf(out[v] - M) / S;
}

extern "C" void kernel_launch(void* const* d_in, const int* in_sizes, int n_in,
                              void* d_out, int out_size, void* d_ws, size_t ws_size,
                              hipStream_t stream) {
    const float* sen_emb  = (const float*)d_in[0];
    const float* hiddens  = (const float*)d_in[1];
    const float* dim_out  = (const float*)d_in[2];
    const float* Wi[4]; const float* Wh[4]; const float* bi[4]; const float* bh[4];
    for (int g = 0; g < 4; ++g) {
        Wi[g] = (const float*)d_in[3 + 4 * g];
        Wh[g] = (const float*)d_in[4 + 4 * g];
        bi[g] = (const float*)d_in[5 + 4 * g];
        bh[g] = (const float*)d_in[6 + 4 * g];
    }
    const float* cur_h    = (const float*)d_in[19];
    const float* cur_cell = (const float*)d_in[20];
    const int*   pos_idx  = (const int*)d_in[21];
    float* out = (float*)d_out;
    float* ws  = (float*)d_ws;

    float* partial = ws;                            // 128*1024 = 131072 floats
    float* x       = ws + 131072;                   // 2049 (pad 2056)
    float* hv      = ws + 131072 + 2056;            // 1024
    float* pmax    = ws + 131072 + 2056 + 1024;     // 197 (pad 256)
    float* psum    = pmax + 256;                    // 197 (pad 256)
    float* part    = psum + 256;                    // KS * PSTR = 403456 floats

    k1_colsum<<<STRIPES, 256, 0, stream>>>(hiddens, partial);
    k2_buildx<<<4, 256, 0, stream>>>(partial, sen_emb, pos_idx, x);
    k3_gates<<<HDIM, 256, 0, stream>>>(x, cur_h, cur_cell,
        Wi[0], Wh[0], bi[0], bh[0],
        Wi[1], Wh[1], bi[1], bh[1],
        Wi[2], Wh[2], bi[2], bh[2],
        Wi[3], Wh[3], bi[3], bh[3], hv);
    dim3 g4(NBLK_V, KS);
    k4a_partial<<<g4, 256, 0, stream>>>(hv, dim_out, part);
    k4b_combine<<<NBLK_V, 256, 0, stream>>>(part, out, pmax, psum);
    k5_softmax<<<NBLK_V, 256, 0, stream>>>(pmax, psum, out);
}